// Round 1
// 405.484 us; speedup vs baseline: 1.3836x; 1.3836x over previous
//
#include <hip/hip_runtime.h>
#include <hip/hip_bf16.h>

typedef __hip_bfloat16 bf16;
typedef __attribute__((ext_vector_type(8))) short bf16x8v;  // 8 bf16 = 4 VGPRs
typedef __attribute__((ext_vector_type(4))) float f32x4v;   // MFMA accumulator

// ---------- helpers -----------------------------------------------------------
__device__ __forceinline__ float bfbits2f(unsigned short h) {
    union { unsigned int u; float f; } v; v.u = ((unsigned int)h) << 16; return v.f;
}
__device__ __forceinline__ unsigned short f2bfbits(float f) {
    bf16 h = __float2bfloat16(f);
    unsigned short s;
    __builtin_memcpy(&s, &h, 2);
    return s;
}
__device__ __forceinline__ float load1_any(const void* p, long idx, bool f32) {
    if (f32) return ((const float*)p)[idx];
    return bfbits2f(((const unsigned short*)p)[idx]);
}
__device__ __forceinline__ float4 loadbf4(const bf16* p) {
    ushort4 u = *reinterpret_cast<const ushort4*>(p);
    return make_float4(bfbits2f(u.x), bfbits2f(u.y), bfbits2f(u.z), bfbits2f(u.w));
}
__device__ __forceinline__ void store_bf4(bf16* p, float a, float b, float c, float d) {
    ushort4 o;
    o.x = f2bfbits(a); o.y = f2bfbits(b); o.z = f2bfbits(c); o.w = f2bfbits(d);
    *reinterpret_cast<ushort4*>(p) = o;
}
// async global->LDS, 16B per lane; LDS dest = wave-uniform base + lane*16
__device__ __forceinline__ void gl16(const void* g, void* l) {
    __builtin_amdgcn_global_load_lds(
        (const __attribute__((address_space(1))) unsigned int*)g,
        (__attribute__((address_space(3))) unsigned int*)l, 16, 0, 0);
}

// ---------- input dtype detection (flag=1: read raw inputs as fp32) -----------
// Parallel/vectorized: 1024 threads, 16 independent uint4 loads each.
// Same sample set as before: even shorts of the first 131072 shorts.
__global__ __launch_bounds__(1024)
void detect_kernel(const unsigned short* __restrict__ x, int* __restrict__ flag) {
    const int tid = threadIdx.x;
    int zc = 0, hc = 0;
    const uint4* xv = (const uint4*)x;
#pragma unroll
    for (int p = 0; p < 16; ++p) {
        uint4 v = xv[p * 1024 + tid];
        unsigned s0 = v.x & 0xFFFFu, s1 = v.y & 0xFFFFu;
        unsigned s2 = v.z & 0xFFFFu, s3 = v.w & 0xFFFFu;
        zc += (int)(s0 == 0) + (int)(s1 == 0) + (int)(s2 == 0) + (int)(s3 == 0);
        hc += (int)(((s0 >> 7) & 0xFFu) >= 0x90u) + (int)(((s1 >> 7) & 0xFFu) >= 0x90u)
            + (int)(((s2 >> 7) & 0xFFu) >= 0x90u) + (int)(((s3 >> 7) & 0xFFu) >= 0x90u);
    }
#pragma unroll
    for (int off = 32; off > 0; off >>= 1) {
        zc += __shfl_down(zc, off);
        hc += __shfl_down(hc, off);
    }
    __shared__ int rz[16], rh[16];
    if ((tid & 63) == 0) { rz[tid >> 6] = zc; rh[tid >> 6] = hc; }
    __syncthreads();
    if (tid == 0) {
        int Z = 0, H = 0;
#pragma unroll
        for (int i = 0; i < 16; ++i) { Z += rz[i]; H += rh[i]; }
        *flag = (Z > 60000 || H > 256) ? 1 : 0;
    }
}

__global__ void diag_kernel(float* __restrict__ out, float val) {
    if (threadIdx.x == 0) out[0] = val;
}

// ---------- fused weight convert: all 6 weight tensors in one dispatch --------
__global__ __launch_bounds__(256)
void convert6_kernel(const void* __restrict__ s0, const void* __restrict__ s1,
                     const void* __restrict__ s2, const void* __restrict__ s3,
                     const void* __restrict__ s4, const void* __restrict__ s5,
                     bf16* __restrict__ dst, const int* __restrict__ dflag) {
    const bool f32 = (*dflag != 0);
    for (long i = (long)blockIdx.x * 256 + threadIdx.x; i < 4456448;
         i += (long)gridDim.x * 256) {
        const void* s; long o;
        if (i < 131072)       { s = s0; o = i; }
        else if (i < 196608)  { s = s1; o = i - 131072; }
        else if (i < 262144)  { s = s2; o = i - 196608; }
        else if (i < 2359296) { s = s3; o = i - 262144; }
        else if (i < 3407872) { s = s4; o = i - 2359296; }
        else                  { s = s5; o = i - 3407872; }
        dst[i] = __float2bfloat16(load1_any(s, o, f32));
    }
}

// ---------- transpose+convert: x[bg][256][1024] raw -> xT[z][1024][256] bf16 --
// Merged spa/freq: z<zsplit reads x1, else x2.
__global__ __launch_bounds__(256)
void xpose_conv_kernel(const void* __restrict__ x1, const void* __restrict__ x2,
                       bf16* __restrict__ dst, int bofs, int zsplit,
                       const int* __restrict__ dflag) {
    const bool f32 = (*dflag != 0);
    __shared__ float t[64][65];
    const int ch0 = blockIdx.y * 64, n0 = blockIdx.x * 64, z = blockIdx.z;
    const bool hiz = (z >= zsplit);
    const int zl = hiz ? z - zsplit : z;
    const void* x = hiz ? x2 : x1;
    const long sb = (long)(zl + bofs) * 262144, db = (long)z * 262144;
    const int tid = threadIdx.x;
#pragma unroll
    for (int p = 0; p < 16; ++p) {
        int e = tid + p * 256; int sch = e >> 6, sn = e & 63;
        t[sch][sn] = load1_any(x, sb + (long)(ch0 + sch) * 1024 + n0 + sn, f32);
    }
    __syncthreads();
#pragma unroll
    for (int p = 0; p < 16; ++p) {
        int e = tid + p * 256; int dn = e >> 6, dch = e & 63;
        dst[db + (long)(n0 + dn) * 256 + ch0 + dch] = __float2bfloat16(t[dch][dn]);
    }
}

// ---------- bf16 transpose: src[z][1024][1024] -> dst[z][1024][1024]^T --------
__global__ __launch_bounds__(256)
void xpose_bf_kernel(const bf16* __restrict__ src, bf16* __restrict__ dst) {
    __shared__ float t[64][65];
    const int c0 = blockIdx.x * 64, r0 = blockIdx.y * 64;
    const long b = (long)blockIdx.z * 1048576;
    const int tid = threadIdx.x;
#pragma unroll
    for (int p = 0; p < 16; ++p) {
        int e = tid + p * 256; int r = e >> 6, c = e & 63;
        t[r][c] = __bfloat162float(src[b + (long)(r0 + r) * 1024 + c0 + c]);
    }
    __syncthreads();
#pragma unroll
    for (int p = 0; p < 16; ++p) {
        int e = tid + p * 256; int r = e >> 6, c = e & 63;
        dst[b + (long)(c0 + r) * 1024 + r0 + c] = __float2bfloat16(t[c][r]);
    }
}

// ---------- unified NT MFMA GEMM, 2-phase pipelined, global_load_lds ----------
// D[z][m][n] = sum_k A[z][m][k] * B[z][n][k]   (both operands k-contiguous)
// 128x128 tile / block (4 waves, each 64x64 via 4x4 grid of 16x16x32 MFMA).
// z-split: z<zsplit uses {A1,B1,out1,bias1,res1}, else {A2,B2,...} with zl=z-zsplit.
// K-split (concat along K): k0>=ksplit reads Bb + (k0-ksplit) + kOff2.
// LDS seg swizzle: physical(row,s) holds logical(row, s ^ ((row>>1)&3));
// applied on the *global source* (gload_lds dest must stay linear) and on reads.
// EPI: 0 plain bf16 out | 1 +bias[row] bf16 | 2 *scale+bias[col] bf16 | 3 +res fp32 out
template <int EPI>
__global__ __launch_bounds__(256)
void mfma_nt(const bf16* __restrict__ A1, const bf16* __restrict__ A2,
             long aBatch, int ldA,
             const bf16* __restrict__ B1, const bf16* __restrict__ B2,
             long bBatch, int ldB, int ksplit, long kOff2,
             void* __restrict__ out1, void* __restrict__ out2,
             long oBatch, int ldO, int K, float scale,
             const void* __restrict__ bias1, const void* __restrict__ bias2,
             const void* __restrict__ res1, const void* __restrict__ res2,
             long rBatch, int bofs, int zsplit,
             const int* __restrict__ dflag) {
    __shared__ short As[2][4096];   // [buf][128 rows x 32 shorts]  8KB each
    __shared__ short Bs[2][4096];
    const int tid  = threadIdx.x;
    const int lane = tid & 63, wave = tid >> 6;
    const int quad = lane >> 4, lrow = lane & 15;
    const int wm = (wave >> 1) * 64, wn = (wave & 1) * 64;
    const int n0 = blockIdx.x * 128, m0 = blockIdx.y * 128;
    const int z  = blockIdx.z;
    const bool hiz = (z >= zsplit);
    const int zl = hiz ? z - zsplit : z;
    const int srow = tid >> 2, sseg = tid & 3;
    const int sl = sseg ^ ((srow >> 1) & 3);        // staging: swizzled logical seg
    const int xq = quad ^ ((lrow >> 1) & 3);        // read: physical seg for my quad

    const bf16* Ab = (hiz ? A2 : A1) + (long)zl * aBatch;
    const bf16* Bb = (hiz ? B2 : B1) + (long)zl * bBatch;

    auto stage = [&](int buf, int k0) {
        const bf16* asrc = Ab + (long)k0;
        const bf16* bsrc = Bb + ((k0 < ksplit) ? (long)k0 : (long)(k0 - ksplit) + kOff2);
        const bf16* ga0 = asrc + (long)(m0 + srow) * ldA + sl * 8;
        const bf16* ga1 = asrc + (long)(m0 + 64 + srow) * ldA + sl * 8;
        const bf16* gb0 = bsrc + (long)(n0 + srow) * ldB + sl * 8;
        const bf16* gb1 = bsrc + (long)(n0 + 64 + srow) * ldB + sl * 8;
        short* la = &As[buf][wave * 512];
        short* lb = &Bs[buf][wave * 512];
        gl16(ga0, la);
        gl16(ga1, la + 2048);
        gl16(gb0, lb);
        gl16(gb1, lb + 2048);
    };

    f32x4v acc[4][4] = {};
    const int nt = K >> 5;
    int cur = 0;
    stage(0, 0);
    asm volatile("s_waitcnt vmcnt(0)" ::: "memory");
    __builtin_amdgcn_s_barrier();

    for (int t = 0; t < nt; ++t) {
        if (t + 1 < nt) stage(cur ^ 1, (t + 1) << 5);   // prefetch under compute
        bf16x8v bfr[4];
#pragma unroll
        for (int j = 0; j < 4; ++j) {
            int r = wn + j * 16 + lrow;
            bfr[j] = *(const bf16x8v*)&Bs[cur][r * 32 + xq * 8];
        }
#pragma unroll
        for (int i = 0; i < 4; ++i) {
            int r = wm + i * 16 + lrow;
            bf16x8v af = *(const bf16x8v*)&As[cur][r * 32 + xq * 8];
#pragma unroll
            for (int j = 0; j < 4; ++j)
                acc[i][j] = __builtin_amdgcn_mfma_f32_16x16x32_bf16(af, bfr[j], acc[i][j], 0, 0, 0);
        }
        if (t + 1 < nt) {
            __builtin_amdgcn_sched_barrier(0);          // rule 18: pin reads/MFMA here
            asm volatile("s_waitcnt vmcnt(0) lgkmcnt(0)" ::: "memory");
            __builtin_amdgcn_s_barrier();
            cur ^= 1;
        }
    }

    const bool f32 = (*dflag != 0);
    const void* bias = hiz ? bias2 : bias1;
    if (EPI <= 2) {
        bf16* O = (bf16*)(hiz ? out2 : out1) + (long)zl * oBatch;
#pragma unroll
        for (int i = 0; i < 4; ++i) {
            int row0 = m0 + wm + i * 16 + quad * 4;
            float rb[4] = {0.f, 0.f, 0.f, 0.f};
            if (EPI == 1) {
#pragma unroll
                for (int r = 0; r < 4; ++r) rb[r] = load1_any(bias, row0 + r, f32);
            }
#pragma unroll
            for (int j = 0; j < 4; ++j) {
                int col = n0 + wn + j * 16 + lrow;
                float cb = (EPI == 2) ? load1_any(bias, col, f32) : 0.f;
#pragma unroll
                for (int r = 0; r < 4; ++r) {
                    float vv = acc[i][j][r];
                    if (EPI == 1) vv += rb[r];
                    if (EPI == 2) vv = vv * scale + cb;
                    O[(long)(row0 + r) * ldO + col] = __float2bfloat16(vv);
                }
            }
        }
    } else {
        float* O = (float*)(hiz ? out2 : out1);
        const void* res = hiz ? res2 : res1;
        const long ob  = (long)(zl + bofs) * oBatch;
        const long rbb = (long)(zl + bofs) * rBatch;
#pragma unroll
        for (int i = 0; i < 4; ++i) {
            int row0 = m0 + wm + i * 16 + quad * 4;
#pragma unroll
            for (int j = 0; j < 4; ++j) {
                int col = n0 + wn + j * 16 + lrow;
#pragma unroll
                for (int r = 0; r < 4; ++r) {
                    float rv = load1_any(res, rbb + (long)(row0 + r) * ldO + col, f32);
                    O[ob + (long)(row0 + r) * ldO + col] = acc[i][j][r] + rv;
                }
            }
        }
    }
}

// ---------- LayerNorm over last dim (1024), bf16 in-place ---------------------
__global__ __launch_bounds__(256)
void layernorm_kernel(bf16* __restrict__ x, const void* __restrict__ g,
                      const void* __restrict__ beta, const int* __restrict__ dflag) {
    const bool f32 = (*dflag != 0);
    bf16* p = x + (long)blockIdx.x * 1024;
    const int tid = threadIdx.x;
    float4 v = loadbf4(p + tid * 4);
    float s  = v.x + v.y + v.z + v.w;
    float ss = v.x * v.x + v.y * v.y + v.z * v.z + v.w * v.w;
#pragma unroll
    for (int off = 32; off > 0; off >>= 1) {
        s  += __shfl_down(s, off);
        ss += __shfl_down(ss, off);
    }
    __shared__ float sh[8];
    __shared__ float sh_mu, sh_rs;
    if ((tid & 63) == 0) { sh[tid >> 6] = s; sh[4 + (tid >> 6)] = ss; }
    __syncthreads();
    if (tid == 0) {
        float S  = sh[0] + sh[1] + sh[2] + sh[3];
        float SS = sh[4] + sh[5] + sh[6] + sh[7];
        float mu = S * (1.0f / 1024.0f);
        float var = SS * (1.0f / 1024.0f) - mu * mu;
        sh_mu = mu;
        sh_rs = rsqrtf(fmaxf(var, 0.0f) + 1e-5f);
    }
    __syncthreads();
    float mu = sh_mu, rs = sh_rs;
    float gx = load1_any(g, tid * 4 + 0, f32), gy = load1_any(g, tid * 4 + 1, f32);
    float gz = load1_any(g, tid * 4 + 2, f32), gw = load1_any(g, tid * 4 + 3, f32);
    float bx = load1_any(beta, tid * 4 + 0, f32), by = load1_any(beta, tid * 4 + 1, f32);
    float bz = load1_any(beta, tid * 4 + 2, f32), bw = load1_any(beta, tid * 4 + 3, f32);
    store_bf4(p + tid * 4,
              (v.x - mu) * rs * gx + bx, (v.y - mu) * rs * gy + by,
              (v.z - mu) * rs * gz + bz, (v.w - mu) * rs * gw + bw);
}

// ---------- row softmax over last dim (1024), bf16 in-place -------------------
__global__ __launch_bounds__(256)
void softmax_kernel(bf16* __restrict__ x) {
    bf16* p = x + (long)blockIdx.x * 1024;
    const int tid = threadIdx.x;
    float4 v = loadbf4(p + tid * 4);
    float m = fmaxf(fmaxf(v.x, v.y), fmaxf(v.z, v.w));
#pragma unroll
    for (int off = 32; off > 0; off >>= 1) m = fmaxf(m, __shfl_down(m, off));
    __shared__ float sh[8];
    __shared__ float shM, shS;
    if ((tid & 63) == 0) sh[tid >> 6] = m;
    __syncthreads();
    if (tid == 0) shM = fmaxf(fmaxf(sh[0], sh[1]), fmaxf(sh[2], sh[3]));
    __syncthreads();
    float M = shM;
    v.x = __expf(v.x - M);
    v.y = __expf(v.y - M);
    v.z = __expf(v.z - M);
    v.w = __expf(v.w - M);
    float s = v.x + v.y + v.z + v.w;
#pragma unroll
    for (int off = 32; off > 0; off >>= 1) s += __shfl_down(s, off);
    if ((tid & 63) == 0) sh[4 + (tid >> 6)] = s;
    __syncthreads();
    if (tid == 0) shS = sh[4] + sh[5] + sh[6] + sh[7];
    __syncthreads();
    float inv = 1.0f / shS;
    store_bf4(p + tid * 4, v.x * inv, v.y * inv, v.z * inv, v.w * inv);
}

// ---------- host ---------------------------------------------------------------
extern "C" void kernel_launch(void* const* d_in, const int* in_sizes, int n_in,
                              void* d_out, int out_size, void* d_ws, size_t ws_size,
                              hipStream_t stream) {
    const void* x_spa  = d_in[0];
    const void* x_freq = d_in[1];
    const void* w_cdc  = d_in[2];
    const void* b_cdc  = d_in[3];
    const void* w_sv   = d_in[4];
    const void* b_sv   = d_in[5];
    const void* w_fv   = d_in[6];
    const void* b_fv   = d_in[7];
    const void* ln_w   = d_in[8];
    const void* ln_b   = d_in[9];
    const void* w_qk   = d_in[10];
    const void* w_spa  = d_in[11];
    const void* b_spa  = d_in[12];
    const void* w_frq  = d_in[13];
    const void* b_frq  = d_in[14];
    float* out = (float*)d_out;          // fp32 output

    const int B = 16, C = 256;
    const long XB = 262144;              // [256][1024] or [1024][256] tiles
    const long PB = 1048576;             // [1024][1024]

    // ws: 4KB header | bf16 weights (4,456,448 elems) | G * per-batch
    int*  dflag = (int*)d_ws;
    bf16* wb    = (bf16*)((char*)d_ws + 4096);
    bf16* w_cdc_b = wb;                       // 131072  (256 x 512)
    bf16* w_sv_b  = w_cdc_b + 131072;         // 65536   (256 x 256)
    bf16* w_fv_b  = w_sv_b  + 65536;          // 65536
    bf16* w_qk_b  = w_fv_b  + 65536;          // 2097152 (2048 x 1024)
    bf16* w_spa_b = w_qk_b  + 2097152;        // 1048576 (1024 x 1024)
    bf16* w_frq_b = w_spa_b + 1048576;        // 1048576
    bf16* pb      = w_frq_b + 1048576;

    const size_t fixedB = 4096 + 4456448ull * 2;
    const size_t perB   = 13107200ull;        // (9*XB + 4*PB)*2 bytes = 12.5 MiB/batch
    size_t avail = (ws_size > fixedB) ? (ws_size - fixedB) : 0;
    long gmax = (long)(avail / perB);
    const bool wsOK = (gmax >= 1);
    int G = wsOK ? (int)(gmax > 16 ? 16 : gmax) : 1;

    bf16* xT   = pb;                      // [2z][1024][256]  (spa: z<g, frq: z>=g)
    bf16* xln  = xT   + 2L * G * XB;      // [z][256][1024]
    bf16* kb   = xln  + (long)G * XB;     // [z][256][1024]
    bf16* qT   = kb   + (long)G * XB;     // [z][1024][256]
    bf16* TT   = qT   + (long)G * XB;     // [2z][1024][256]
    bf16* vb   = TT   + 2L * G * XB;      // [2z][256][1024]
    bf16* attp = vb   + 2L * G * XB;      // [2z][1024][1024]
    bf16* attpT= attp + 2L * G * PB;      // [2z][1024][1024]

    dim3 blk(256);
    detect_kernel<<<dim3(1), dim3(1024), 0, stream>>>((const unsigned short*)x_spa, dflag);

    if (!wsOK) {
        float mb = (float)(ws_size >> 20);
        diag_kernel<<<dim3(1), dim3(64), 0, stream>>>(out, 1000.0f * (mb + 1.0f));
        return;
    }

    // all weights -> bf16 in one dispatch
    convert6_kernel<<<dim3(4352), blk, 0, stream>>>(w_cdc, w_sv, w_fv, w_qk, w_spa, w_frq,
                                                    wb, dflag);

    for (int b0 = 0; b0 < B; b0 += G) {
        int g = (B - b0 < G) ? (B - b0) : G;

        // x_spa/x_freq -> xT[2g] (bf16, [n][ch])
        xpose_conv_kernel<<<dim3(16, 4, 2 * g), blk, 0, stream>>>(
            x_spa, x_freq, xT, b0, g, dflag);

        // v (both branches): vb[z] = w_{s,f}v @ x  (rowbias)
        mfma_nt<1><<<dim3(8, 2, 2 * g), blk, 0, stream>>>(
            w_sv_b, w_fv_b, 0, 256,
            xT, xT + (long)g * XB, XB, 256, 256, 0,
            vb, vb + (long)g * XB, XB, 1024, 256, 1.0f,
            b_sv, b_fv, nullptr, nullptr, 0, 0, g, dflag);

        // xln = w_cdc @ cat(x_spa, x_freq)  (rowbias, K split at 256)
        mfma_nt<1><<<dim3(8, 2, g), blk, 0, stream>>>(
            w_cdc_b, w_cdc_b, 0, 512,
            xT, xT, XB, 256, 256, (long)g * XB,
            xln, xln, XB, 1024, 512, 1.0f,
            b_cdc, b_cdc, nullptr, nullptr, 0, 0, g, dflag);
        layernorm_kernel<<<dim3(g * C), blk, 0, stream>>>(xln, ln_w, ln_b, dflag);

        // k[c][m] = xln @ w_qk[1024:]^T
        mfma_nt<0><<<dim3(8, 2, g), blk, 0, stream>>>(
            xln, xln, XB, 1024,
            w_qk_b + 1048576, w_qk_b + 1048576, 0, 1024, 1024, 0,
            kb, kb, XB, 1024, 1024, 1.0f,
            nullptr, nullptr, nullptr, nullptr, 0, 0, g, dflag);
        // qT[n][c] = w_qk[:1024] @ xln^T
        mfma_nt<0><<<dim3(2, 8, g), blk, 0, stream>>>(
            w_qk_b, w_qk_b, 0, 1024,
            xln, xln, XB, 1024, 1024, 0,
            qT, qT, XB, 256, 1024, 1.0f,
            nullptr, nullptr, nullptr, nullptr, 0, 0, g, dflag);

        // TT (both): TT[z][j][c] = w_{spa,frq} @ k^T
        mfma_nt<0><<<dim3(2, 8, 2 * g), blk, 0, stream>>>(
            w_spa_b, w_frq_b, 0, 1024,
            kb, kb, XB, 1024, 1024, 0,
            TT, TT + (long)g * XB, XB, 256, 1024, 1.0f,
            nullptr, nullptr, nullptr, nullptr, 0, 0, g, dflag);

        // attp (both): attp[z][n][j] = scale * qT . TT + bias[col]
        mfma_nt<2><<<dim3(8, 8, 2 * g), blk, 0, stream>>>(
            qT, qT, XB, 256,
            TT, TT + (long)g * XB, XB, 256, 256, 0,
            attp, attp + (long)g * PB, PB, 1024, 256, 0.03125f,
            b_spa, b_frq, nullptr, nullptr, 0, 0, g, dflag);

        softmax_kernel<<<dim3(2 * g * 1024), blk, 0, stream>>>(attp);
        xpose_bf_kernel<<<dim3(16, 16, 2 * g), blk, 0, stream>>>(attp, attpT);

        // out (both): out = v @ attp^T + x   (fp32 out)
        mfma_nt<3><<<dim3(8, 2, 2 * g), blk, 0, stream>>>(
            vb, vb + (long)g * XB, XB, 1024,
            attpT, attpT + (long)g * PB, PB, 1024, 1024, 0,
            out, out + 4194304, XB, 1024, 1024, 1.0f,
            nullptr, nullptr, x_spa, x_freq, XB, b0, g, dflag);
    }
}

// Round 2
// 371.504 us; speedup vs baseline: 1.5101x; 1.0915x over previous
//
#include <hip/hip_runtime.h>
#include <hip/hip_bf16.h>

typedef __hip_bfloat16 bf16;
typedef __attribute__((ext_vector_type(8))) short bf16x8v;  // 8 bf16 = 4 VGPRs
typedef __attribute__((ext_vector_type(4))) float f32x4v;   // MFMA accumulator

// ---------- helpers -----------------------------------------------------------
__device__ __forceinline__ float bfbits2f(unsigned short h) {
    union { unsigned int u; float f; } v; v.u = ((unsigned int)h) << 16; return v.f;
}
__device__ __forceinline__ unsigned short f2bfbits(float f) {
    bf16 h = __float2bfloat16(f);
    unsigned short s;
    __builtin_memcpy(&s, &h, 2);
    return s;
}
__device__ __forceinline__ float load1_any(const void* p, long idx, bool f32) {
    if (f32) return ((const float*)p)[idx];
    return bfbits2f(((const unsigned short*)p)[idx]);
}
__device__ __forceinline__ float4 loadbf4(const bf16* p) {
    ushort4 u = *reinterpret_cast<const ushort4*>(p);
    return make_float4(bfbits2f(u.x), bfbits2f(u.y), bfbits2f(u.z), bfbits2f(u.w));
}
__device__ __forceinline__ void store_bf4(bf16* p, float a, float b, float c, float d) {
    ushort4 o;
    o.x = f2bfbits(a); o.y = f2bfbits(b); o.z = f2bfbits(c); o.w = f2bfbits(d);
    *reinterpret_cast<ushort4*>(p) = o;
}
// async global->LDS, 16B per lane; LDS dest = wave-uniform base + lane*16
__device__ __forceinline__ void gl16(const void* g, void* l) {
    __builtin_amdgcn_global_load_lds(
        (const __attribute__((address_space(1))) unsigned int*)g,
        (__attribute__((address_space(3))) unsigned int*)l, 16, 0, 0);
}

// ---------- input dtype detection (flag=1: read raw inputs as fp32) -----------
__global__ __launch_bounds__(1024)
void detect_kernel(const unsigned short* __restrict__ x, int* __restrict__ flag) {
    const int tid = threadIdx.x;
    int zc = 0, hc = 0;
    const uint4* xv = (const uint4*)x;
#pragma unroll
    for (int p = 0; p < 16; ++p) {
        uint4 v = xv[p * 1024 + tid];
        unsigned s0 = v.x & 0xFFFFu, s1 = v.y & 0xFFFFu;
        unsigned s2 = v.z & 0xFFFFu, s3 = v.w & 0xFFFFu;
        zc += (int)(s0 == 0) + (int)(s1 == 0) + (int)(s2 == 0) + (int)(s3 == 0);
        hc += (int)(((s0 >> 7) & 0xFFu) >= 0x90u) + (int)(((s1 >> 7) & 0xFFu) >= 0x90u)
            + (int)(((s2 >> 7) & 0xFFu) >= 0x90u) + (int)(((s3 >> 7) & 0xFFu) >= 0x90u);
    }
#pragma unroll
    for (int off = 32; off > 0; off >>= 1) {
        zc += __shfl_down(zc, off);
        hc += __shfl_down(hc, off);
    }
    __shared__ int rz[16], rh[16];
    if ((tid & 63) == 0) { rz[tid >> 6] = zc; rh[tid >> 6] = hc; }
    __syncthreads();
    if (tid == 0) {
        int Z = 0, H = 0;
#pragma unroll
        for (int i = 0; i < 16; ++i) { Z += rz[i]; H += rh[i]; }
        *flag = (Z > 60000 || H > 256) ? 1 : 0;
    }
}

__global__ void diag_kernel(float* __restrict__ out, float val) {
    if (threadIdx.x == 0) out[0] = val;
}

// ---------- fused weight convert: all 6 weight tensors in one dispatch --------
__global__ __launch_bounds__(256)
void convert6_kernel(const void* __restrict__ s0, const void* __restrict__ s1,
                     const void* __restrict__ s2, const void* __restrict__ s3,
                     const void* __restrict__ s4, const void* __restrict__ s5,
                     bf16* __restrict__ dst, const int* __restrict__ dflag) {
    const bool f32 = (*dflag != 0);
    for (long i = (long)blockIdx.x * 256 + threadIdx.x; i < 4456448;
         i += (long)gridDim.x * 256) {
        const void* s; long o;
        if (i < 131072)       { s = s0; o = i; }
        else if (i < 196608)  { s = s1; o = i - 131072; }
        else if (i < 262144)  { s = s2; o = i - 196608; }
        else if (i < 2359296) { s = s3; o = i - 262144; }
        else if (i < 3407872) { s = s4; o = i - 2359296; }
        else                  { s = s5; o = i - 3407872; }
        dst[i] = __float2bfloat16(load1_any(s, o, f32));
    }
}

// ---------- transpose+convert: x[bg][256][1024] raw -> xT[z][1024][256] bf16 --
__global__ __launch_bounds__(256)
void xpose_conv_kernel(const void* __restrict__ x1, const void* __restrict__ x2,
                       bf16* __restrict__ dst, int bofs, int zsplit,
                       const int* __restrict__ dflag) {
    const bool f32 = (*dflag != 0);
    __shared__ float t[64][65];
    const int ch0 = blockIdx.y * 64, n0 = blockIdx.x * 64, z = blockIdx.z;
    const bool hiz = (z >= zsplit);
    const int zl = hiz ? z - zsplit : z;
    const void* x = hiz ? x2 : x1;
    const long sb = (long)(zl + bofs) * 262144, db = (long)z * 262144;
    const int tid = threadIdx.x;
#pragma unroll
    for (int p = 0; p < 16; ++p) {
        int e = tid + p * 256; int sch = e >> 6, sn = e & 63;
        t[sch][sn] = load1_any(x, sb + (long)(ch0 + sch) * 1024 + n0 + sn, f32);
    }
    __syncthreads();
#pragma unroll
    for (int p = 0; p < 16; ++p) {
        int e = tid + p * 256; int dn = e >> 6, dch = e & 63;
        dst[db + (long)(n0 + dn) * 256 + ch0 + dch] = __float2bfloat16(t[dch][dn]);
    }
}

// ---------- softmax stats: per-row max and 1/sum(exp) -------------------------
// One wave per row (4 rows / block). Row = 1024 bf16.
__global__ __launch_bounds__(256)
void sm_stats_kernel(const bf16* __restrict__ x, float2* __restrict__ st) {
    const int tid = threadIdx.x, lane = tid & 63, w = tid >> 6;
    const long row = (long)blockIdx.x * 4 + w;
    const bf16* p = x + row * 1024;
    float4 v[4];
    float m = -3.4e38f;
#pragma unroll
    for (int c = 0; c < 4; ++c) {
        v[c] = loadbf4(p + lane * 4 + c * 256);
        m = fmaxf(m, fmaxf(fmaxf(v[c].x, v[c].y), fmaxf(v[c].z, v[c].w)));
    }
#pragma unroll
    for (int off = 32; off > 0; off >>= 1) m = fmaxf(m, __shfl_xor(m, off));
    float s = 0.f;
#pragma unroll
    for (int c = 0; c < 4; ++c)
        s += __expf(v[c].x - m) + __expf(v[c].y - m) + __expf(v[c].z - m) + __expf(v[c].w - m);
#pragma unroll
    for (int off = 32; off > 0; off >>= 1) s += __shfl_xor(s, off);
    if (lane == 0) st[row] = make_float2(m, 1.0f / s);
}

// ---------- fused normalize + transpose: attpT = softmax(attp)^T --------------
__global__ __launch_bounds__(256)
void xpose_norm_kernel(const bf16* __restrict__ src, bf16* __restrict__ dst,
                       const float2* __restrict__ st) {
    __shared__ float t[64][65];
    const int c0 = blockIdx.x * 64, r0 = blockIdx.y * 64;
    const long b = (long)blockIdx.z * 1048576;
    const long sb = (long)blockIdx.z * 1024;
    const int tid = threadIdx.x;
#pragma unroll
    for (int p = 0; p < 16; ++p) {
        int e = tid + p * 256; int r = e >> 6, c = e & 63;
        float2 ms = st[sb + r0 + r];           // wave-uniform (r fixed per wave)
        t[r][c] = __expf(__bfloat162float(src[b + (long)(r0 + r) * 1024 + c0 + c]) - ms.x) * ms.y;
    }
    __syncthreads();
#pragma unroll
    for (int p = 0; p < 16; ++p) {
        int e = tid + p * 256; int r = e >> 6, c = e & 63;
        dst[b + (long)(c0 + r) * 1024 + r0 + c] = __float2bfloat16(t[c][r]);
    }
}

// ---------- unified NT MFMA GEMM, depth-3 counted-vmcnt pipeline --------------
// D[z][m][n] = sum_k A[z][m][k] * B[z][n][k]   (both operands k-contiguous)
// 128x128 tile / block (4 waves, each 64x64 via 4x4 grid of 16x16x32 MFMA).
// 3 LDS buffers; steady state keeps 2 stages (8 gl16 loads) in flight:
//   wait vmcnt(8) -> barrier -> ds_read -> lgkmcnt(0) -> barrier -> stage(t+3) -> MFMA
// LDS seg swizzle on global source + read side (gload_lds dest stays linear).
// EPI: 0 plain bf16 out | 1 +bias[row] bf16 | 2 *scale+bias[col] bf16 | 3 +res fp32 out
template <int EPI>
__global__ __launch_bounds__(256)
void mfma_nt(const bf16* __restrict__ A1, const bf16* __restrict__ A2,
             long aBatch, int ldA,
             const bf16* __restrict__ B1, const bf16* __restrict__ B2,
             long bBatch, int ldB, int ksplit, long kOff2,
             void* __restrict__ out1, void* __restrict__ out2,
             long oBatch, int ldO, int K, float scale,
             const void* __restrict__ bias1, const void* __restrict__ bias2,
             const void* __restrict__ res1, const void* __restrict__ res2,
             long rBatch, int bofs, int zsplit,
             const int* __restrict__ dflag) {
    __shared__ short As[3][4096];   // [buf][128 rows x 32 shorts]  8KB each
    __shared__ short Bs[3][4096];
    const int tid  = threadIdx.x;
    const int lane = tid & 63, wave = tid >> 6;
    const int quad = lane >> 4, lrow = lane & 15;
    const int wm = (wave >> 1) * 64, wn = (wave & 1) * 64;
    const int n0 = blockIdx.x * 128, m0 = blockIdx.y * 128;
    const int z  = blockIdx.z;
    const bool hiz = (z >= zsplit);
    const int zl = hiz ? z - zsplit : z;
    const int srow = tid >> 2, sseg = tid & 3;
    const int sl = sseg ^ ((srow >> 1) & 3);        // staging: swizzled logical seg
    const int xq = quad ^ ((lrow >> 1) & 3);        // read: physical seg for my quad

    const bf16* Ab = (hiz ? A2 : A1) + (long)zl * aBatch;
    const bf16* Bb = (hiz ? B2 : B1) + (long)zl * bBatch;

    auto stage = [&](int buf, int k0) {
        const bf16* asrc = Ab + (long)k0;
        const bf16* bsrc = Bb + ((k0 < ksplit) ? (long)k0 : (long)(k0 - ksplit) + kOff2);
        const bf16* ga0 = asrc + (long)(m0 + srow) * ldA + sl * 8;
        const bf16* ga1 = asrc + (long)(m0 + 64 + srow) * ldA + sl * 8;
        const bf16* gb0 = bsrc + (long)(n0 + srow) * ldB + sl * 8;
        const bf16* gb1 = bsrc + (long)(n0 + 64 + srow) * ldB + sl * 8;
        short* la = &As[buf][wave * 512];
        short* lb = &Bs[buf][wave * 512];
        gl16(ga0, la);
        gl16(ga1, la + 2048);
        gl16(gb0, lb);
        gl16(gb1, lb + 2048);
    };

    f32x4v acc[4][4] = {};
    const int nt = K >> 5;
    stage(0, 0);
    if (nt > 1) stage(1, 32);
    if (nt > 2) stage(2, 64);

    int cur = 0;
    for (int t = 0; t < nt; ++t) {
        const int rem = nt - 1 - t;
        if (rem >= 2)      asm volatile("s_waitcnt vmcnt(8)" ::: "memory");
        else if (rem == 1) asm volatile("s_waitcnt vmcnt(4)" ::: "memory");
        else               asm volatile("s_waitcnt vmcnt(0)" ::: "memory");
        __builtin_amdgcn_s_barrier();            // all waves' tile-t loads landed
        __builtin_amdgcn_sched_barrier(0);
        bf16x8v bfr[4], afr[4];
#pragma unroll
        for (int j = 0; j < 4; ++j)
            bfr[j] = *(const bf16x8v*)&Bs[cur][(wn + j * 16 + lrow) * 32 + xq * 8];
#pragma unroll
        for (int i = 0; i < 4; ++i)
            afr[i] = *(const bf16x8v*)&As[cur][(wm + i * 16 + lrow) * 32 + xq * 8];
        asm volatile("s_waitcnt lgkmcnt(0)" ::: "memory");
        __builtin_amdgcn_sched_barrier(0);       // rule 18: MFMA can't hoist above
        __builtin_amdgcn_s_barrier();            // all waves done reading buf[cur]
        __builtin_amdgcn_sched_barrier(0);       // keep stage below the barrier
        if (t + 3 < nt) stage(cur, (t + 3) << 5);
#pragma unroll
        for (int i = 0; i < 4; ++i)
#pragma unroll
            for (int j = 0; j < 4; ++j)
                acc[i][j] = __builtin_amdgcn_mfma_f32_16x16x32_bf16(afr[i], bfr[j], acc[i][j], 0, 0, 0);
        cur = (cur == 2) ? 0 : cur + 1;
    }

    const bool f32 = (*dflag != 0);
    const void* bias = hiz ? bias2 : bias1;
    if (EPI <= 2) {
        bf16* O = (bf16*)(hiz ? out2 : out1) + (long)zl * oBatch;
#pragma unroll
        for (int i = 0; i < 4; ++i) {
            int row0 = m0 + wm + i * 16 + quad * 4;
            float rb[4] = {0.f, 0.f, 0.f, 0.f};
            if (EPI == 1) {
#pragma unroll
                for (int r = 0; r < 4; ++r) rb[r] = load1_any(bias, row0 + r, f32);
            }
#pragma unroll
            for (int j = 0; j < 4; ++j) {
                int col = n0 + wn + j * 16 + lrow;
                float cb = (EPI == 2) ? load1_any(bias, col, f32) : 0.f;
#pragma unroll
                for (int r = 0; r < 4; ++r) {
                    float vv = acc[i][j][r];
                    if (EPI == 1) vv += rb[r];
                    if (EPI == 2) vv = vv * scale + cb;
                    O[(long)(row0 + r) * ldO + col] = __float2bfloat16(vv);
                }
            }
        }
    } else {
        float* O = (float*)(hiz ? out2 : out1);
        const void* res = hiz ? res2 : res1;
        const long ob  = (long)(zl + bofs) * oBatch;
        const long rbb = (long)(zl + bofs) * rBatch;
#pragma unroll
        for (int i = 0; i < 4; ++i) {
            int row0 = m0 + wm + i * 16 + quad * 4;
#pragma unroll
            for (int j = 0; j < 4; ++j) {
                int col = n0 + wn + j * 16 + lrow;
#pragma unroll
                for (int r = 0; r < 4; ++r) {
                    float rv = load1_any(res, rbb + (long)(row0 + r) * ldO + col, f32);
                    O[ob + (long)(row0 + r) * ldO + col] = acc[i][j][r] + rv;
                }
            }
        }
    }
}

// ---------- LayerNorm over last dim (1024), bf16 in-place ---------------------
__global__ __launch_bounds__(256)
void layernorm_kernel(bf16* __restrict__ x, const void* __restrict__ g,
                      const void* __restrict__ beta, const int* __restrict__ dflag) {
    const bool f32 = (*dflag != 0);
    bf16* p = x + (long)blockIdx.x * 1024;
    const int tid = threadIdx.x;
    float4 v = loadbf4(p + tid * 4);
    float s  = v.x + v.y + v.z + v.w;
    float ss = v.x * v.x + v.y * v.y + v.z * v.z + v.w * v.w;
#pragma unroll
    for (int off = 32; off > 0; off >>= 1) {
        s  += __shfl_down(s, off);
        ss += __shfl_down(ss, off);
    }
    __shared__ float sh[8];
    __shared__ float sh_mu, sh_rs;
    if ((tid & 63) == 0) { sh[tid >> 6] = s; sh[4 + (tid >> 6)] = ss; }
    __syncthreads();
    if (tid == 0) {
        float S  = sh[0] + sh[1] + sh[2] + sh[3];
        float SS = sh[4] + sh[5] + sh[6] + sh[7];
        float mu = S * (1.0f / 1024.0f);
        float var = SS * (1.0f / 1024.0f) - mu * mu;
        sh_mu = mu;
        sh_rs = rsqrtf(fmaxf(var, 0.0f) + 1e-5f);
    }
    __syncthreads();
    float mu = sh_mu, rs = sh_rs;
    float gx = load1_any(g, tid * 4 + 0, f32), gy = load1_any(g, tid * 4 + 1, f32);
    float gz = load1_any(g, tid * 4 + 2, f32), gw = load1_any(g, tid * 4 + 3, f32);
    float bx = load1_any(beta, tid * 4 + 0, f32), by = load1_any(beta, tid * 4 + 1, f32);
    float bz = load1_any(beta, tid * 4 + 2, f32), bw = load1_any(beta, tid * 4 + 3, f32);
    store_bf4(p + tid * 4,
              (v.x - mu) * rs * gx + bx, (v.y - mu) * rs * gy + by,
              (v.z - mu) * rs * gz + bz, (v.w - mu) * rs * gw + bw);
}

// ---------- host ---------------------------------------------------------------
extern "C" void kernel_launch(void* const* d_in, const int* in_sizes, int n_in,
                              void* d_out, int out_size, void* d_ws, size_t ws_size,
                              hipStream_t stream) {
    const void* x_spa  = d_in[0];
    const void* x_freq = d_in[1];
    const void* w_cdc  = d_in[2];
    const void* b_cdc  = d_in[3];
    const void* w_sv   = d_in[4];
    const void* b_sv   = d_in[5];
    const void* w_fv   = d_in[6];
    const void* b_fv   = d_in[7];
    const void* ln_w   = d_in[8];
    const void* ln_b   = d_in[9];
    const void* w_qk   = d_in[10];
    const void* w_spa  = d_in[11];
    const void* b_spa  = d_in[12];
    const void* w_frq  = d_in[13];
    const void* b_frq  = d_in[14];
    float* out = (float*)d_out;          // fp32 output

    const int B = 16, C = 256;
    const long XB = 262144;              // [256][1024] or [1024][256] tiles
    const long PB = 1048576;             // [1024][1024]

    // ws: 4KB header | bf16 weights (4,456,448 elems) | G * per-batch
    int*  dflag = (int*)d_ws;
    bf16* wb    = (bf16*)((char*)d_ws + 4096);
    bf16* w_cdc_b = wb;                       // 131072  (256 x 512)
    bf16* w_sv_b  = w_cdc_b + 131072;         // 65536   (256 x 256)
    bf16* w_fv_b  = w_sv_b  + 65536;          // 65536
    bf16* w_qk_b  = w_fv_b  + 65536;          // 2097152 (2048 x 1024)
    bf16* w_spa_b = w_qk_b  + 2097152;        // 1048576 (1024 x 1024)
    bf16* w_frq_b = w_spa_b + 1048576;        // 1048576
    bf16* pb      = w_frq_b + 1048576;

    const size_t fixedB = 4096 + 4456448ull * 2;
    const size_t perB   = 13123584ull;        // (9*XB + 4*PB)*2 + 2*1024*8 bytes
    size_t avail = (ws_size > fixedB) ? (ws_size - fixedB) : 0;
    long gmax = (long)(avail / perB);
    const bool wsOK = (gmax >= 1);
    int G = wsOK ? (int)(gmax > 16 ? 16 : gmax) : 1;

    bf16* xT   = pb;                      // [2z][1024][256]  (spa: z<g, frq: z>=g)
    bf16* xln  = xT   + 2L * G * XB;      // [z][256][1024]
    bf16* kb   = xln  + (long)G * XB;     // [z][256][1024]
    bf16* qT   = kb   + (long)G * XB;     // [z][1024][256]
    bf16* TT   = qT   + (long)G * XB;     // [2z][1024][256]
    bf16* vb   = TT   + 2L * G * XB;      // [2z][256][1024]
    bf16* attp = vb   + 2L * G * XB;      // [2z][1024][1024]
    bf16* attpT= attp + 2L * G * PB;      // [2z][1024][1024]
    float2* stats = (float2*)(attpT + 2L * G * PB);  // [2z][1024] {max, 1/sum}

    dim3 blk(256);
    detect_kernel<<<dim3(1), dim3(1024), 0, stream>>>((const unsigned short*)x_spa, dflag);

    if (!wsOK) {
        float mb = (float)(ws_size >> 20);
        diag_kernel<<<dim3(1), dim3(64), 0, stream>>>(out, 1000.0f * (mb + 1.0f));
        return;
    }

    // all weights -> bf16 in one dispatch
    convert6_kernel<<<dim3(4352), blk, 0, stream>>>(w_cdc, w_sv, w_fv, w_qk, w_spa, w_frq,
                                                    wb, dflag);

    for (int b0 = 0; b0 < B; b0 += G) {
        int g = (B - b0 < G) ? (B - b0) : G;

        // x_spa/x_freq -> xT[2g] (bf16, [n][ch])
        xpose_conv_kernel<<<dim3(16, 4, 2 * g), blk, 0, stream>>>(
            x_spa, x_freq, xT, b0, g, dflag);

        // v (both branches): vb[z] = w_{s,f}v @ x  (rowbias)
        mfma_nt<1><<<dim3(8, 2, 2 * g), blk, 0, stream>>>(
            w_sv_b, w_fv_b, 0, 256,
            xT, xT + (long)g * XB, XB, 256, 256, 0,
            vb, vb + (long)g * XB, XB, 1024, 256, 1.0f,
            b_sv, b_fv, nullptr, nullptr, 0, 0, g, dflag);

        // xln = w_cdc @ cat(x_spa, x_freq)  (rowbias, K split at 256)
        mfma_nt<1><<<dim3(8, 2, g), blk, 0, stream>>>(
            w_cdc_b, w_cdc_b, 0, 512,
            xT, xT, XB, 256, 256, (long)g * XB,
            xln, xln, XB, 1024, 512, 1.0f,
            b_cdc, b_cdc, nullptr, nullptr, 0, 0, g, dflag);
        layernorm_kernel<<<dim3(g * C), blk, 0, stream>>>(xln, ln_w, ln_b, dflag);

        // k[c][m] = xln @ w_qk[1024:]^T
        mfma_nt<0><<<dim3(8, 2, g), blk, 0, stream>>>(
            xln, xln, XB, 1024,
            w_qk_b + 1048576, w_qk_b + 1048576, 0, 1024, 1024, 0,
            kb, kb, XB, 1024, 1024, 1.0f,
            nullptr, nullptr, nullptr, nullptr, 0, 0, g, dflag);
        // qT[n][c] = w_qk[:1024] @ xln^T
        mfma_nt<0><<<dim3(2, 8, g), blk, 0, stream>>>(
            w_qk_b, w_qk_b, 0, 1024,
            xln, xln, XB, 1024, 1024, 0,
            qT, qT, XB, 256, 1024, 1.0f,
            nullptr, nullptr, nullptr, nullptr, 0, 0, g, dflag);

        // TT (both): TT[z][j][c] = w_{spa,frq} @ k^T
        mfma_nt<0><<<dim3(2, 8, 2 * g), blk, 0, stream>>>(
            w_spa_b, w_frq_b, 0, 1024,
            kb, kb, XB, 1024, 1024, 0,
            TT, TT + (long)g * XB, XB, 256, 1024, 1.0f,
            nullptr, nullptr, nullptr, nullptr, 0, 0, g, dflag);

        // attp (both): attp[z][n][j] = scale * qT . TT + bias[col]  (raw scores)
        mfma_nt<2><<<dim3(8, 8, 2 * g), blk, 0, stream>>>(
            qT, qT, XB, 256,
            TT, TT + (long)g * XB, XB, 256, 256, 0,
            attp, attp + (long)g * PB, PB, 1024, 256, 0.03125f,
            b_spa, b_frq, nullptr, nullptr, 0, 0, g, dflag);

        // softmax stats (per row), then fused normalize+transpose
        sm_stats_kernel<<<dim3(512 * g), blk, 0, stream>>>(attp, stats);
        xpose_norm_kernel<<<dim3(16, 16, 2 * g), blk, 0, stream>>>(attp, attpT, stats);

        // out (both): out = v @ attp^T + x   (fp32 out)
        mfma_nt<3><<<dim3(8, 2, 2 * g), blk, 0, stream>>>(
            vb, vb + (long)g * XB, XB, 1024,
            attpT, attpT + (long)g * PB, PB, 1024, 1024, 0,
            out, out + 4194304, XB, 1024, 1024, 1.0f,
            nullptr, nullptr, x_spa, x_freq, XB, b0, g, dflag);
    }
}